// Round 1
// baseline (10954.168 us; speedup 1.0000x reference)
//
#include <hip/hip_runtime.h>
#include <hip/hip_bf16.h>
#include <stdint.h>
#include <stddef.h>

typedef short bf16x8 __attribute__((ext_vector_type(8)));
typedef float f32x4 __attribute__((ext_vector_type(4)));
typedef int i32x4 __attribute__((ext_vector_type(4)));
typedef unsigned short u16;
typedef unsigned int u32;

// ---------- helpers: fp32 -> bf16 (RNE) split ----------
__device__ __forceinline__ u16 f2bf(float x) {
  u32 u = __builtin_bit_cast(u32, x);
  u32 r = (u + 0x7fffu + ((u >> 16) & 1u)) >> 16;
  return (u16)r;
}
__device__ __forceinline__ float bf2f(u16 h) {
  u32 u = ((u32)h) << 16;
  return __builtin_bit_cast(float, u);
}
__device__ __forceinline__ void split2(float a, float b, u32& hw, u32& lw) {
  u16 ha = f2bf(a), hb = f2bf(b);
  float ra = a - bf2f(ha), rb = b - bf2f(hb);
  hw = (u32)ha | ((u32)hb << 16);
  lw = (u32)f2bf(ra) | ((u32)f2bf(rb) << 16);
}

// ---------- prep: transpose + bf16-split a 1024x1024 weight ----------
// W[k][c] fp32 row-major  ->  WT_hi[c][k], WT_lo[c][k] bf16
__global__ void wsplit(const float* __restrict__ W, u16* __restrict__ Thi, u16* __restrict__ Tlo) {
  __shared__ float tile[32][33];
  const int bx = blockIdx.x * 32;  // c base
  const int by = blockIdx.y * 32;  // k base
  const int tx = threadIdx.x, ty = threadIdx.y;  // (32,8)
#pragma unroll
  for (int r = 0; r < 4; ++r) {
    int ky = ty + 8 * r;
    tile[ky][tx] = W[(size_t)(by + ky) * 1024 + bx + tx];
  }
  __syncthreads();
#pragma unroll
  for (int r = 0; r < 4; ++r) {
    int row = ty + 8 * r;           // c-local
    float v = tile[tx][row];        // = W[by+tx][bx+row]
    u16 hi = f2bf(v);
    u16 lo = f2bf(v - bf2f(hi));
    Thi[(size_t)(bx + row) * 1024 + by + tx] = hi;
    Tlo[(size_t)(bx + row) * 1024 + by + tx] = lo;
  }
}

// ---------- prep: init h-broadcast buffer (parity 0) in MFMA-A-fragment order + zero flags ----------
// fragment layout: element (n,k) with g=n>>4,row=n&15 stored at
//   [((g*32 + (k>>5))*64 + row + 16*((k&31)>>3))*8 + (k&7)]
__global__ void hinit(const float* __restrict__ h0, u16* __restrict__ hb_hi, u16* __restrict__ hb_lo,
                      int* __restrict__ flags) {
  int idx = blockIdx.x * 256 + threadIdx.x;  // 65536 total
  float v = h0[idx];
  int n = idx >> 10, k = idx & 1023;
  int g = n >> 4, row = n & 15;
  int pos = ((g * 32 + (k >> 5)) * 64 + row + 16 * ((k & 31) >> 3)) * 8 + (k & 7);
  u16 hi = f2bf(v);
  u16 lo = f2bf(v - bf2f(hi));
  hb_hi[pos] = hi;
  hb_lo[pos] = lo;
  if (idx < 256) flags[idx] = 0;
}

// ---------- phase 1: xw = x @ Wx + b  (bf16x3 MFMA, 128x128 tile, BK=32) ----------
#define LDT 40  // padded LDS row stride (bf16 elems) -> conflict-free ds_read_b128

__global__ __launch_bounds__(256, 2) void xw_gemm(
    const float* __restrict__ X, const u16* __restrict__ BThi, const u16* __restrict__ BTlo,
    const float* __restrict__ bias, float* __restrict__ out) {
  __shared__ u16 Ah[128 * LDT], Al[128 * LDT], Bh[128 * LDT], Bl[128 * LDT];
  const int tid = threadIdx.x;
  const int lane = tid & 63, wave = tid >> 6;
  const int wm = wave >> 1, wn = wave & 1;           // 2x2 waves, 64x64 each
  const int m0 = blockIdx.y * 128, n0 = blockIdx.x * 128;
  const int arow = tid >> 1, afo = (tid & 1) << 4;   // A: 2 threads/row, 16 floats each
  const int bcol = tid >> 1, bko = (tid & 1) << 4;   // B: 2 threads/col, 16 bf16 each
  const float* Xa = X + (size_t)(m0 + arow) * 1024 + afo;
  const u16* bhp = BThi + (size_t)(n0 + bcol) * 1024 + bko;
  const u16* blp = BTlo + (size_t)(n0 + bcol) * 1024 + bko;

  f32x4 acc[4][4] = {};

  const int aoff = (wm * 64 + (lane & 15)) * LDT + ((lane >> 4) << 3);
  const int boff = (wn * 64 + (lane & 15)) * LDT + ((lane >> 4) << 3);

  for (int k0 = 0; k0 < 1024; k0 += 32) {
    const float4* xp = (const float4*)(Xa + k0);
    float4 f0 = xp[0], f1 = xp[1], f2 = xp[2], f3 = xp[3];
    i32x4 gbh0 = *(const i32x4*)(bhp + k0);
    i32x4 gbh1 = *(const i32x4*)(bhp + k0 + 8);
    i32x4 gbl0 = *(const i32x4*)(blp + k0);
    i32x4 gbl1 = *(const i32x4*)(blp + k0 + 8);
    u32 hw0, hw1, hw2, hw3, hw4, hw5, hw6, hw7;
    u32 lw0, lw1, lw2, lw3, lw4, lw5, lw6, lw7;
    split2(f0.x, f0.y, hw0, lw0); split2(f0.z, f0.w, hw1, lw1);
    split2(f1.x, f1.y, hw2, lw2); split2(f1.z, f1.w, hw3, lw3);
    split2(f2.x, f2.y, hw4, lw4); split2(f2.z, f2.w, hw5, lw5);
    split2(f3.x, f3.y, hw6, lw6); split2(f3.z, f3.w, hw7, lw7);
    __syncthreads();
    *(i32x4*)&Ah[arow * LDT + afo]     = i32x4{(int)hw0, (int)hw1, (int)hw2, (int)hw3};
    *(i32x4*)&Ah[arow * LDT + afo + 8] = i32x4{(int)hw4, (int)hw5, (int)hw6, (int)hw7};
    *(i32x4*)&Al[arow * LDT + afo]     = i32x4{(int)lw0, (int)lw1, (int)lw2, (int)lw3};
    *(i32x4*)&Al[arow * LDT + afo + 8] = i32x4{(int)lw4, (int)lw5, (int)lw6, (int)lw7};
    *(i32x4*)&Bh[bcol * LDT + bko]     = gbh0;
    *(i32x4*)&Bh[bcol * LDT + bko + 8] = gbh1;
    *(i32x4*)&Bl[bcol * LDT + bko]     = gbl0;
    *(i32x4*)&Bl[bcol * LDT + bko + 8] = gbl1;
    __syncthreads();

    bf16x8 a_h[4], a_l[4], b_h[4], b_l[4];
#pragma unroll
    for (int i = 0; i < 4; ++i) {
      a_h[i] = *(const bf16x8*)(Ah + aoff + i * 16 * LDT);
      a_l[i] = *(const bf16x8*)(Al + aoff + i * 16 * LDT);
      b_h[i] = *(const bf16x8*)(Bh + boff + i * 16 * LDT);
      b_l[i] = *(const bf16x8*)(Bl + boff + i * 16 * LDT);
    }
#pragma unroll
    for (int i = 0; i < 4; ++i)
#pragma unroll
      for (int j = 0; j < 4; ++j)
        acc[i][j] = __builtin_amdgcn_mfma_f32_16x16x32_bf16(a_h[i], b_h[j], acc[i][j], 0, 0, 0);
#pragma unroll
    for (int i = 0; i < 4; ++i)
#pragma unroll
      for (int j = 0; j < 4; ++j)
        acc[i][j] = __builtin_amdgcn_mfma_f32_16x16x32_bf16(a_h[i], b_l[j], acc[i][j], 0, 0, 0);
#pragma unroll
    for (int i = 0; i < 4; ++i)
#pragma unroll
      for (int j = 0; j < 4; ++j)
        acc[i][j] = __builtin_amdgcn_mfma_f32_16x16x32_bf16(a_l[i], b_h[j], acc[i][j], 0, 0, 0);
  }
  // epilogue: C[row=(l>>4)*4+r, col=l&15] (verified layout), add bias, store fp32
  const int ccol = n0 + wn * 64 + (lane & 15);
  const int crow = m0 + wm * 64 + ((lane >> 4) << 2);
#pragma unroll
  for (int j = 0; j < 4; ++j) {
    float bv = bias[ccol + j * 16];
#pragma unroll
    for (int i = 0; i < 4; ++i)
#pragma unroll
      for (int r = 0; r < 4; ++r)
        out[(size_t)(crow + i * 16 + r) * 1024 + ccol + j * 16] = acc[i][j][r] + bv;
  }
}

// ---------- phase 2: sequential scan, dataflow-flag sync ----------
// grid = 256 WGs x 64 threads. WG (g,c): rows [g*16,g*16+16), cols [c*16,c*16+16).
__global__ __launch_bounds__(64, 1) void rnn_scan(
    const u16* __restrict__ WThi, const u16* __restrict__ WTlo,
    float* __restrict__ out,
    u16* __restrict__ hb_hi0, u16* __restrict__ hb_lo0,
    u16* __restrict__ hb_hi1, u16* __restrict__ hb_lo1,
    int* __restrict__ flags) {
  __shared__ u16 Ws_h[16 * 1032];  // Wh slice, padded stride 1032 -> conflict-free b128 reads
  __shared__ u16 Ws_l[16 * 1032];
  const int lane = threadIdx.x;
  const int c = blockIdx.x & 63, g = blockIdx.x >> 6;

  // persistent Wh slice load (16 cols x 1024 k, hi+lo)
  for (int it = 0; it < 32; ++it) {
    int idx = it * 64 + lane;
    int r = idx >> 7, cu = idx & 127;
    *(i32x4*)&Ws_h[r * 1032 + cu * 8] = *(const i32x4*)(WThi + (size_t)(c * 16 + r) * 1024 + cu * 8);
    *(i32x4*)&Ws_l[r * 1032 + cu * 8] = *(const i32x4*)(WTlo + (size_t)(c * 16 + r) * 1024 + cu * 8);
  }
  __syncthreads();

  const int fb = g << 6;
  const int ldsoff = (lane & 15) * 1032 + ((lane >> 4) << 3);
  const int rq = lane >> 4, colL = lane & 15;
  // producer scatter: output (row, col=c*16+colL) lands in consumer-A-fragment order
  const int plq = 16 * (((c & 1) << 1) + (colL >> 3));
  const size_t pbase = ((size_t)(g * 32 + (c >> 1)) * 64) * 8 + (lane & 7);

  for (int s = 0; s < 512; ++s) {
    // wait for all 64 producers of this row-group to have published h_s
    while (!__all(__hip_atomic_load(&flags[fb + lane], __ATOMIC_RELAXED, __HIP_MEMORY_SCOPE_AGENT) >= s))
      __builtin_amdgcn_s_sleep(2);
    __threadfence();  // acquire: invalidate caches before reading cross-XCD h

    const u16* hb_h = (s & 1) ? hb_hi1 : hb_hi0;
    const u16* hb_l = (s & 1) ? hb_lo1 : hb_lo0;
    u16* ob_h = (s & 1) ? hb_hi0 : hb_hi1;
    u16* ob_l = (s & 1) ? hb_lo0 : hb_lo1;
    const i32x4* pah = (const i32x4*)hb_h + (size_t)(g * 32) * 64 + lane;
    const i32x4* pal = (const i32x4*)hb_l + (size_t)(g * 32) * 64 + lane;

    f32x4 a0 = {}, a1 = {}, a2 = {};
#pragma unroll 4
    for (int kk = 0; kk < 32; ++kk) {
      bf16x8 ah = __builtin_bit_cast(bf16x8, pah[kk * 64]);
      bf16x8 al = __builtin_bit_cast(bf16x8, pal[kk * 64]);
      bf16x8 bh = *(const bf16x8*)&Ws_h[ldsoff + kk * 32];
      bf16x8 bl = *(const bf16x8*)&Ws_l[ldsoff + kk * 32];
      a0 = __builtin_amdgcn_mfma_f32_16x16x32_bf16(ah, bh, a0, 0, 0, 0);
      a1 = __builtin_amdgcn_mfma_f32_16x16x32_bf16(ah, bl, a1, 0, 0, 0);
      a2 = __builtin_amdgcn_mfma_f32_16x16x32_bf16(al, bh, a2, 0, 0, 0);
    }

#pragma unroll
    for (int r = 0; r < 4; ++r) {
      int row = (rq << 2) + r;
      int n = (g << 4) + row;
      size_t oidx = ((size_t)n * 512 + s) * 1024 + (c << 4) + colL;
      float pre = out[oidx] + a0[r] + a1[r] + a2[r];
      float hv = tanhf(pre);
      out[oidx] = hv;
      u16 hi = f2bf(hv);
      u16 lo = f2bf(hv - bf2f(hi));
      size_t p = pbase + (size_t)(row + plq) * 8;
      ob_h[p] = hi;
      ob_l[p] = lo;
    }
    __threadfence();  // release: make h_{s+1} + out visible agent-wide
    if (lane == 0)
      __hip_atomic_store(&flags[fb + c], s + 1, __ATOMIC_RELAXED, __HIP_MEMORY_SCOPE_AGENT);
  }
}

// ---------- launch ----------
extern "C" void kernel_launch(void* const* d_in, const int* in_sizes, int n_in,
                              void* d_out, int out_size, void* d_ws, size_t ws_size,
                              hipStream_t stream) {
  const float* x    = (const float*)d_in[0];
  const float* h0   = (const float*)d_in[1];
  const float* Wx   = (const float*)d_in[2];
  const float* Wh   = (const float*)d_in[3];
  const float* bias = (const float*)d_in[4];
  float* out = (float*)d_out;
  char* ws = (char*)d_ws;

  const size_t MB2 = (size_t)1 << 21;
  u16* WxThi = (u16*)(ws);
  u16* WxTlo = (u16*)(ws + MB2);
  u16* WhThi = (u16*)(ws + 2 * MB2);
  u16* WhTlo = (u16*)(ws + 3 * MB2);
  u16* hb    = (u16*)(ws + 4 * MB2);
  u16* hb_hi0 = hb;
  u16* hb_lo0 = hb + 65536;
  u16* hb_hi1 = hb + 2 * 65536;
  u16* hb_lo1 = hb + 3 * 65536;
  int* flags = (int*)(ws + 4 * MB2 + 4 * 65536 * sizeof(u16));

  wsplit<<<dim3(32, 32), dim3(32, 8), 0, stream>>>(Wx, WxThi, WxTlo);
  wsplit<<<dim3(32, 32), dim3(32, 8), 0, stream>>>(Wh, WhThi, WhTlo);
  hinit<<<256, 256, 0, stream>>>(h0, hb_hi0, hb_lo0, flags);
  xw_gemm<<<dim3(8, 256), 256, 0, stream>>>(x, WxThi, WxTlo, bias, out);
  rnn_scan<<<256, 64, 0, stream>>>(WhThi, WhTlo, out, hb_hi0, hb_lo0, hb_hi1, hb_lo1, flags);
}

// Round 2
// 4260.116 us; speedup vs baseline: 2.5713x; 2.5713x over previous
//
#include <hip/hip_runtime.h>
#include <hip/hip_bf16.h>
#include <stdint.h>
#include <stddef.h>

typedef short bf16x8 __attribute__((ext_vector_type(8)));
typedef float f32x4 __attribute__((ext_vector_type(4)));
typedef int i32x4 __attribute__((ext_vector_type(4)));
typedef unsigned short u16;
typedef unsigned int u32;
typedef unsigned long long u64;

#define SCOPE_AGENT __HIP_MEMORY_SCOPE_AGENT

// ---------- helpers: fp32 -> bf16 (RNE) split ----------
__device__ __forceinline__ u16 f2bf(float x) {
  u32 u = __builtin_bit_cast(u32, x);
  u32 r = (u + 0x7fffu + ((u >> 16) & 1u)) >> 16;
  return (u16)r;
}
__device__ __forceinline__ float bf2f(u16 h) {
  u32 u = ((u32)h) << 16;
  return __builtin_bit_cast(float, u);
}
__device__ __forceinline__ void split2(float a, float b, u32& hw, u32& lw) {
  u16 ha = f2bf(a), hb = f2bf(b);
  float ra = a - bf2f(ha), rb = b - bf2f(hb);
  hw = (u32)ha | ((u32)hb << 16);
  lw = (u32)f2bf(ra) | ((u32)f2bf(rb) << 16);
}
// pack h value as (bf16_hi << 16) | bf16_lo
__device__ __forceinline__ u32 pack_hl(float v) {
  u16 hi = f2bf(v);
  u16 lo = f2bf(v - bf2f(hi));
  return ((u32)hi << 16) | (u32)lo;
}

// ---------- prep: transpose + bf16-split a 1024x1024 weight ----------
__global__ void wsplit(const float* __restrict__ W, u16* __restrict__ Thi, u16* __restrict__ Tlo) {
  __shared__ float tile[32][33];
  const int bx = blockIdx.x * 32;  // c base
  const int by = blockIdx.y * 32;  // k base
  const int tx = threadIdx.x, ty = threadIdx.y;  // (32,8)
#pragma unroll
  for (int r = 0; r < 4; ++r) {
    int ky = ty + 8 * r;
    tile[ky][tx] = W[(size_t)(by + ky) * 1024 + bx + tx];
  }
  __syncthreads();
#pragma unroll
  for (int r = 0; r < 4; ++r) {
    int row = ty + 8 * r;           // c-local
    float v = tile[tx][row];        // = W[by+tx][bx+row]
    u16 hi = f2bf(v);
    u16 lo = f2bf(v - bf2f(hi));
    Thi[(size_t)(bx + row) * 1024 + by + tx] = hi;
    Tlo[(size_t)(bx + row) * 1024 + by + tx] = lo;
  }
}

// ---------- prep: packed h0 broadcast buffer (parity 0) + zero flags ----------
// hb layout: [n][k] row-major u32 words, word = (hi<<16)|lo. Stored via
// agent-scope atomics so the words are at the coherence point (rnn_scan reads
// them with L2-bypassing loads).
__global__ void hinit(const float* __restrict__ h0, u32* __restrict__ hb0, int* __restrict__ flags) {
  int idx = blockIdx.x * 256 + threadIdx.x;  // 65536 total
  __hip_atomic_store(&hb0[idx], pack_hl(h0[idx]), __ATOMIC_RELAXED, SCOPE_AGENT);
  if (idx < 256) __hip_atomic_store(&flags[idx], 0, __ATOMIC_RELAXED, SCOPE_AGENT);
}

// ---------- phase 1: xw = x @ Wx + b  (bf16x3 MFMA, 128x128 tile, BK=32) ----------
#define LDT 40  // padded LDS row stride (bf16 elems)

__global__ __launch_bounds__(256, 2) void xw_gemm(
    const float* __restrict__ X, const u16* __restrict__ BThi, const u16* __restrict__ BTlo,
    const float* __restrict__ bias, float* __restrict__ out) {
  __shared__ u16 Ah[128 * LDT], Al[128 * LDT], Bh[128 * LDT], Bl[128 * LDT];
  const int tid = threadIdx.x;
  const int lane = tid & 63, wave = tid >> 6;
  const int wm = wave >> 1, wn = wave & 1;
  const int m0 = blockIdx.y * 128, n0 = blockIdx.x * 128;
  const int arow = tid >> 1, afo = (tid & 1) << 4;
  const int bcol = tid >> 1, bko = (tid & 1) << 4;
  const float* Xa = X + (size_t)(m0 + arow) * 1024 + afo;
  const u16* bhp = BThi + (size_t)(n0 + bcol) * 1024 + bko;
  const u16* blp = BTlo + (size_t)(n0 + bcol) * 1024 + bko;

  f32x4 acc[4][4] = {};

  const int aoff = (wm * 64 + (lane & 15)) * LDT + ((lane >> 4) << 3);
  const int boff = (wn * 64 + (lane & 15)) * LDT + ((lane >> 4) << 3);

  for (int k0 = 0; k0 < 1024; k0 += 32) {
    const float4* xp = (const float4*)(Xa + k0);
    float4 f0 = xp[0], f1 = xp[1], f2 = xp[2], f3 = xp[3];
    i32x4 gbh0 = *(const i32x4*)(bhp + k0);
    i32x4 gbh1 = *(const i32x4*)(bhp + k0 + 8);
    i32x4 gbl0 = *(const i32x4*)(blp + k0);
    i32x4 gbl1 = *(const i32x4*)(blp + k0 + 8);
    u32 hw0, hw1, hw2, hw3, hw4, hw5, hw6, hw7;
    u32 lw0, lw1, lw2, lw3, lw4, lw5, lw6, lw7;
    split2(f0.x, f0.y, hw0, lw0); split2(f0.z, f0.w, hw1, lw1);
    split2(f1.x, f1.y, hw2, lw2); split2(f1.z, f1.w, hw3, lw3);
    split2(f2.x, f2.y, hw4, lw4); split2(f2.z, f2.w, hw5, lw5);
    split2(f3.x, f3.y, hw6, lw6); split2(f3.z, f3.w, hw7, lw7);
    __syncthreads();
    *(i32x4*)&Ah[arow * LDT + afo]     = i32x4{(int)hw0, (int)hw1, (int)hw2, (int)hw3};
    *(i32x4*)&Ah[arow * LDT + afo + 8] = i32x4{(int)hw4, (int)hw5, (int)hw6, (int)hw7};
    *(i32x4*)&Al[arow * LDT + afo]     = i32x4{(int)lw0, (int)lw1, (int)lw2, (int)lw3};
    *(i32x4*)&Al[arow * LDT + afo + 8] = i32x4{(int)lw4, (int)lw5, (int)lw6, (int)lw7};
    *(i32x4*)&Bh[bcol * LDT + bko]     = gbh0;
    *(i32x4*)&Bh[bcol * LDT + bko + 8] = gbh1;
    *(i32x4*)&Bl[bcol * LDT + bko]     = gbl0;
    *(i32x4*)&Bl[bcol * LDT + bko + 8] = gbl1;
    __syncthreads();

    bf16x8 a_h[4], a_l[4], b_h[4], b_l[4];
#pragma unroll
    for (int i = 0; i < 4; ++i) {
      a_h[i] = *(const bf16x8*)(Ah + aoff + i * 16 * LDT);
      a_l[i] = *(const bf16x8*)(Al + aoff + i * 16 * LDT);
      b_h[i] = *(const bf16x8*)(Bh + boff + i * 16 * LDT);
      b_l[i] = *(const bf16x8*)(Bl + boff + i * 16 * LDT);
    }
#pragma unroll
    for (int i = 0; i < 4; ++i)
#pragma unroll
      for (int j = 0; j < 4; ++j)
        acc[i][j] = __builtin_amdgcn_mfma_f32_16x16x32_bf16(a_h[i], b_h[j], acc[i][j], 0, 0, 0);
#pragma unroll
    for (int i = 0; i < 4; ++i)
#pragma unroll
      for (int j = 0; j < 4; ++j)
        acc[i][j] = __builtin_amdgcn_mfma_f32_16x16x32_bf16(a_h[i], b_l[j], acc[i][j], 0, 0, 0);
#pragma unroll
    for (int i = 0; i < 4; ++i)
#pragma unroll
      for (int j = 0; j < 4; ++j)
        acc[i][j] = __builtin_amdgcn_mfma_f32_16x16x32_bf16(a_l[i], b_h[j], acc[i][j], 0, 0, 0);
  }
  const int ccol = n0 + wn * 64 + (lane & 15);
  const int crow = m0 + wm * 64 + ((lane >> 4) << 2);
#pragma unroll
  for (int j = 0; j < 4; ++j) {
    float bv = bias[ccol + j * 16];
#pragma unroll
    for (int i = 0; i < 4; ++i)
#pragma unroll
      for (int r = 0; r < 4; ++r)
        out[(size_t)(crow + i * 16 + r) * 1024 + ccol + j * 16] = acc[i][j][r] + bv;
  }
}

// ---------- phase 2: sequential scan, fence-free dataflow sync ----------
// All cross-WG traffic (h words, flags) uses relaxed agent-scope atomics
// (sc0 sc1: bypass L1/L2 to the coherent memory side). Release ordering is
// "s_waitcnt vmcnt(0) then flag store"; acquire ordering is program order
// after the poll branch. NO __threadfence (no buffer_wbl2 / buffer_inv).
__global__ __launch_bounds__(64, 1) void rnn_scan(
    const u16* __restrict__ WThi, const u16* __restrict__ WTlo,
    float* __restrict__ out,
    u32* __restrict__ hb0, u32* __restrict__ hb1,
    int* __restrict__ flags) {
  __shared__ u16 Ws_h[16 * 1032];  // Wh slice hi, padded stride
  __shared__ u16 Ws_l[16 * 1032];  // Wh slice lo
  const int lane = threadIdx.x;
  const int c = blockIdx.x & 63, g = blockIdx.x >> 6;

  // persistent Wh slice load (16 cols x 1024 k, hi+lo)
  for (int it = 0; it < 32; ++it) {
    int idx = it * 64 + lane;
    int r = idx >> 7, cu = idx & 127;
    *(i32x4*)&Ws_h[r * 1032 + cu * 8] = *(const i32x4*)(WThi + (size_t)(c * 16 + r) * 1024 + cu * 8);
    *(i32x4*)&Ws_l[r * 1032 + cu * 8] = *(const i32x4*)(WTlo + (size_t)(c * 16 + r) * 1024 + cu * 8);
  }
  __syncthreads();

  const int fb = g << 6;
  const int colL = lane & 15, q = lane >> 4;
  const int ldsoff = colL * 1032 + (q << 3);                  // B-frag: col=colL, k=q*8+j
  const size_t abase = (size_t)(g * 16 + colL) * 512 + q * 4; // u64 index into hb: row=colL, k=q*8
  const size_t pbase = (size_t)(g * 16 + (q << 2)) * 1024 + (c << 4) + colL;  // producer word idx (r=0)

  for (int s = 0; s < 512; ++s) {
    // prefetch xw for this step (WG-private, normal cached loads) — overlaps the barrier wait
    const size_t obase = ((size_t)(g * 16 + (q << 2)) * 512 + s) * 1024 + (c << 4) + colL;
    float xw[4];
#pragma unroll
    for (int r = 0; r < 4; ++r) xw[r] = out[obase + (size_t)r * 512 * 1024];

    // wait for all 64 producers of this row-group to have published h_s
    while (!__all(__hip_atomic_load(&flags[fb + lane], __ATOMIC_RELAXED, SCOPE_AGENT) >= s))
      __builtin_amdgcn_s_sleep(1);
    asm volatile("" ::: "memory");  // keep h loads below the poll

    const u64* pa = (const u64*)((s & 1) ? hb1 : hb0) + abase;
    u32* ob = (s & 1) ? hb0 : hb1;

    f32x4 a0 = {}, a1 = {}, a2 = {};
#pragma unroll 8
    for (int kk = 0; kk < 32; ++kk) {
      u64 w0 = __hip_atomic_load(pa + (size_t)kk * 16 + 0, __ATOMIC_RELAXED, SCOPE_AGENT);
      u64 w1 = __hip_atomic_load(pa + (size_t)kk * 16 + 1, __ATOMIC_RELAXED, SCOPE_AGENT);
      u64 w2 = __hip_atomic_load(pa + (size_t)kk * 16 + 2, __ATOMIC_RELAXED, SCOPE_AGENT);
      u64 w3 = __hip_atomic_load(pa + (size_t)kk * 16 + 3, __ATOMIC_RELAXED, SCOPE_AGENT);
      i32x4 ahv, alv;
      ahv[0] = (int)__builtin_amdgcn_perm((u32)(w0 >> 32), (u32)w0, 0x07060302u);
      alv[0] = (int)__builtin_amdgcn_perm((u32)(w0 >> 32), (u32)w0, 0x05040100u);
      ahv[1] = (int)__builtin_amdgcn_perm((u32)(w1 >> 32), (u32)w1, 0x07060302u);
      alv[1] = (int)__builtin_amdgcn_perm((u32)(w1 >> 32), (u32)w1, 0x05040100u);
      ahv[2] = (int)__builtin_amdgcn_perm((u32)(w2 >> 32), (u32)w2, 0x07060302u);
      alv[2] = (int)__builtin_amdgcn_perm((u32)(w2 >> 32), (u32)w2, 0x05040100u);
      ahv[3] = (int)__builtin_amdgcn_perm((u32)(w3 >> 32), (u32)w3, 0x07060302u);
      alv[3] = (int)__builtin_amdgcn_perm((u32)(w3 >> 32), (u32)w3, 0x05040100u);
      bf16x8 ah = __builtin_bit_cast(bf16x8, ahv);
      bf16x8 al = __builtin_bit_cast(bf16x8, alv);
      bf16x8 bh = *(const bf16x8*)&Ws_h[ldsoff + kk * 32];
      bf16x8 bl = *(const bf16x8*)&Ws_l[ldsoff + kk * 32];
      a0 = __builtin_amdgcn_mfma_f32_16x16x32_bf16(ah, bh, a0, 0, 0, 0);
      a1 = __builtin_amdgcn_mfma_f32_16x16x32_bf16(ah, bl, a1, 0, 0, 0);
      a2 = __builtin_amdgcn_mfma_f32_16x16x32_bf16(al, bh, a2, 0, 0, 0);
    }

#pragma unroll
    for (int r = 0; r < 4; ++r) {
      float hv = tanhf(xw[r] + a0[r] + a1[r] + a2[r]);
      out[obase + (size_t)r * 512 * 1024] = hv;  // normal cached store (WG-private)
      __hip_atomic_store(&ob[pbase + (size_t)r * 1024], pack_hl(hv), __ATOMIC_RELAXED, SCOPE_AGENT);
    }
    // release: drain all VMEM stores (wave-wide) before publishing the flag
    asm volatile("s_waitcnt vmcnt(0)" ::: "memory");
    if (lane == 0)
      __hip_atomic_store(&flags[fb + c], s + 1, __ATOMIC_RELAXED, SCOPE_AGENT);
  }
}

// ---------- launch ----------
extern "C" void kernel_launch(void* const* d_in, const int* in_sizes, int n_in,
                              void* d_out, int out_size, void* d_ws, size_t ws_size,
                              hipStream_t stream) {
  const float* x    = (const float*)d_in[0];
  const float* h0   = (const float*)d_in[1];
  const float* Wx   = (const float*)d_in[2];
  const float* Wh   = (const float*)d_in[3];
  const float* bias = (const float*)d_in[4];
  float* out = (float*)d_out;
  char* ws = (char*)d_ws;

  const size_t MB2 = (size_t)1 << 21;
  u16* WxThi = (u16*)(ws);
  u16* WxTlo = (u16*)(ws + MB2);
  u16* WhThi = (u16*)(ws + 2 * MB2);
  u16* WhTlo = (u16*)(ws + 3 * MB2);
  u32* hb0   = (u32*)(ws + 4 * MB2);
  u32* hb1   = (u32*)(ws + 4 * MB2 + 65536 * sizeof(u32));
  int* flags = (int*)(ws + 4 * MB2 + 2 * 65536 * sizeof(u32));

  wsplit<<<dim3(32, 32), dim3(32, 8), 0, stream>>>(Wx, WxThi, WxTlo);
  wsplit<<<dim3(32, 32), dim3(32, 8), 0, stream>>>(Wh, WhThi, WhTlo);
  hinit<<<256, 256, 0, stream>>>(h0, hb0, flags);
  xw_gemm<<<dim3(8, 256), 256, 0, stream>>>(x, WxThi, WxTlo, bias, out);
  rnn_scan<<<256, 64, 0, stream>>>(WhThi, WhTlo, out, hb0, hb1, flags);
}